// Round 3
// baseline (1015.316 us; speedup 1.0000x reference)
//
#include <hip/hip_runtime.h>
#include <math.h>

#define N_ATOMS 4096
#define N_EDGES 131072

__device__ __forceinline__ float silu_f(float x){ return x / (1.f + expf(-x)); }
__device__ __forceinline__ float sigmoid_f(float x){ return 1.f / (1.f + expf(-x)); }

// ---------- counting sort of edges by destination ----------
__global__ void hist_kernel(const int* __restrict__ edge_index, int* __restrict__ counts){
  int e = blockIdx.x*blockDim.x + threadIdx.x;
  if (e < N_EDGES) atomicAdd(&counts[edge_index[N_EDGES + e]], 1);
}

__global__ void scan_kernel(const int* __restrict__ counts, int* __restrict__ offsets){
  __shared__ int buf[4096];
  int t = threadIdx.x; // 1024 threads
  for (int i=t;i<4096;i+=1024) buf[i]=counts[i];
  __syncthreads();
  for (int off=1; off<4096; off<<=1){
    int v[4];
    #pragma unroll
    for (int k=0;k<4;k++){ int i=t+k*1024; v[k] = (i>=off)?buf[i-off]:0; }
    __syncthreads();
    #pragma unroll
    for (int k=0;k<4;k++){ int i=t+k*1024; buf[i]+=v[k]; }
    __syncthreads();
  }
  for (int i=t;i<4096;i+=1024) offsets[i]=buf[i]-counts[i]; // exclusive
  if (t==0) offsets[4096]=buf[4095];
}

__global__ void scatter_kernel(const int* __restrict__ edge_index, const int* __restrict__ offsets,
                               int* __restrict__ cursor, int* __restrict__ edge_list){
  int e = blockIdx.x*blockDim.x + threadIdx.x;
  if (e < N_EDGES){
    int d = edge_index[N_EDGES + e];
    int pos = atomicAdd(&cursor[d], 1);
    edge_list[offsets[d] + pos] = e;
  }
}

// ---------- per-atom: edge features -> F -> agg -> upd -> qkv ----------
__global__ __launch_bounds__(128) void atom_kernel(
  const int* __restrict__ atomic_numbers, const float* __restrict__ atom_embed,
  const float* __restrict__ edge_vectors, const float* __restrict__ edge_lengths,
  const float* __restrict__ rad_w1, const float* __restrict__ rad_b1,
  const float* __restrict__ rad_w2, const float* __restrict__ rad_b2,
  const float* __restrict__ tp_w, const float* __restrict__ tp_b,
  const float* __restrict__ msg_w1, const float* __restrict__ msg_b1,
  const float* __restrict__ msg_w2, const float* __restrict__ msg_b2,
  const float* __restrict__ attn_w_in, const float* __restrict__ attn_b_in,
  const int* __restrict__ offsets, const int* __restrict__ edge_list,
  float* __restrict__ upd_out, float* __restrict__ qkv_out)
{
  const int a = blockIdx.x, t = threadIdx.x;
  __shared__ float w2[64*128];   // rad_w2, 32 KB
  __shared__ float w1s[8*64];    // rad_w1, 2 KB
  __shared__ float F[128][9];    // per-atom gathered outer products
  __shared__ float rad1_s[64];
  __shared__ float rbs[8];
  __shared__ float comb[192];
  __shared__ float hid_s[128];
  __shared__ float upd_s[128];

  for (int i=t;i<8192;i+=128) w2[i]=rad_w2[i];
  for (int i=t;i<512;i+=128)  w1s[i]=rad_w1[i];
  #pragma unroll
  for (int j=0;j<9;j++) F[t][j]=0.f;
  __syncthreads();

  const int beg = offsets[a];
  const int end = (a == N_ATOMS-1) ? N_EDGES : offsets[a+1];
  const float PI6 = 0.52359877559829887f; // float(pi/6)
  const float b2r = rad_b2[t];
  const float b1r = (t<64) ? rad_b1[t] : 0.f;

  for (int ei=beg; ei<end; ++ei){
    int e = edge_list[ei];
    float vx = edge_vectors[e*3+0], vy = edge_vectors[e*3+1], vz = edge_vectors[e*3+2];
    float d = edge_lengths[e];
    if (t < 8){
      float cut = 0.5f*(cosf(d*PI6)+1.f) * (d<6.f ? 1.f : 0.f);
      float fr  = (float)(t+1)*PI6;          // match reference rounding
      rbs[t] = sinf(d*fr)/d*cut;
    }
    float rn = sqrtf(vx*vx+vy*vy+vz*vz) + 1e-8f;
    float x = vx/rn, y = vy/rn, z = vz/rn;
    float sh[9];
    sh[0]=1.f; sh[1]=y; sh[2]=z; sh[3]=x;
    sh[4]=3.f*z*z-1.f; sh[5]=x*z; sh[6]=y*z; sh[7]=x*y; sh[8]=x*x-y*y;
    __syncthreads();
    if (t<64){
      float r1 = b1r;
      #pragma unroll
      for (int k2=0;k2<8;k2++) r1 += rbs[k2]*w1s[k2*64+t];
      rad1_s[t] = silu_f(r1);
    }
    __syncthreads();
    float r2 = b2r;
    for (int k2=0;k2<64;k2++) r2 += rad1_s[k2]*w2[k2*128+t];
    r2 = silu_f(r2);
    #pragma unroll
    for (int j=0;j<9;j++) F[t][j] += r2*sh[j];
    __syncthreads();
  }

  // agg[a, t] = sum_r F_flat[r] * tp_w[r,t] + deg * tp_b[t]
  float acc = tp_b[t]*(float)(end-beg);
  for (int c=0;c<128;c++) acc += F[c][0]*tp_w[c*128+t];
  for (int c=0;c<128;c++){
    #pragma unroll
    for (int j=0;j<3;j++) acc += F[c][1+j]*tp_w[(128+c*3+j)*128+t];
  }
  for (int c=0;c<128;c++){
    #pragma unroll
    for (int j=0;j<5;j++) acc += F[c][4+j]*tp_w[(512+c*5+j)*128+t];
  }

  if (t<64){
    int zt = atomic_numbers[a];
    comb[t] = atom_embed[zt*64+t];
  }
  comb[64+t] = acc;
  __syncthreads();

  float h = msg_b1[t];
  for (int k2=0;k2<192;k2++) h += comb[k2]*msg_w1[k2*128+t];
  hid_s[t] = silu_f(h);
  __syncthreads();

  float u = msg_b2[t];
  for (int k2=0;k2<128;k2++) u += hid_s[k2]*msg_w2[k2*128+t];
  upd_s[t] = u;
  upd_out[a*128+t] = u;
  __syncthreads();

  #pragma unroll
  for (int p=0;p<3;p++){
    int i = t + p*128;
    float qa = attn_b_in[i];
    for (int k2=0;k2<128;k2++) qa += upd_s[k2]*attn_w_in[i*128+k2];
    qkv_out[a*384+i] = qa;
  }
}

// ---------- flash attention: 4 heads, N=4096, D=32, dense softmax ----------
__global__ __launch_bounds__(256) void attn_kernel(const float* __restrict__ qkv, float* __restrict__ att){
  const int bx = blockIdx.x;
  const int h  = bx >> 7;   // 4 heads
  const int qb = bx & 127;  // 128 query tiles of 32
  const int t  = threadIdx.x;
  const int ql = t >> 3, s = t & 7;
  const int n  = qb*32 + ql;

  __shared__ float Ks[64][33];
  __shared__ float Vs[64][33];

  const float scale = 0.17677669529663687f; // 1/sqrt(32)
  float qv[32];
  #pragma unroll
  for (int d=0; d<32; d++) qv[d] = qkv[n*384 + h*32 + d]*scale;

  float mx = -3e38f, sum = 0.f;
  float acc[32];
  #pragma unroll
  for (int d=0; d<32; d++) acc[d]=0.f;

  for (int kt=0; kt<64; kt++){
    __syncthreads();
    for (int idx=t; idx<2048; idx+=256){
      int m = idx>>5, d = idx&31;
      Ks[m][d] = qkv[(kt*64+m)*384 + 128 + h*32 + d];
      Vs[m][d] = qkv[(kt*64+m)*384 + 256 + h*32 + d];
    }
    __syncthreads();
    for (int m=s; m<64; m+=8){
      float dot = 0.f;
      #pragma unroll
      for (int d=0; d<32; d++) dot += qv[d]*Ks[m][d];
      if (dot <= mx){
        float p = expf(dot-mx);
        sum += p;
        #pragma unroll
        for (int d=0; d<32; d++) acc[d] += p*Vs[m][d];
      } else {
        float c = expf(mx-dot);
        sum = sum*c + 1.f;
        #pragma unroll
        for (int d=0; d<32; d++) acc[d] = acc[d]*c + Vs[m][d];
        mx = dot;
      }
    }
  }

  // merge the 8 key-slices of each query (consecutive lanes, same wave)
  #pragma unroll
  for (int off=1; off<8; off<<=1){
    float mo = __shfl_xor(mx, off, 64);
    float so = __shfl_xor(sum, off, 64);
    float M  = fmaxf(mx, mo);
    float c1 = expf(mx-M), c2 = expf(mo-M);
    sum = sum*c1 + so*c2;
    #pragma unroll
    for (int d=0; d<32; d++){
      float ao = __shfl_xor(acc[d], off, 64);
      acc[d] = acc[d]*c1 + ao*c2;
    }
    mx = M;
  }
  float inv = 1.f/sum;
  #pragma unroll
  for (int k=0;k<4;k++) att[n*128 + h*32 + s*4 + k] = acc[s*4+k]*inv;
}

// ---------- epilogue: attn out proj, gate, final proj ----------
__global__ __launch_bounds__(128) void final_kernel(
  const float* __restrict__ att, const float* __restrict__ upd,
  const float* __restrict__ attn_w_out, const float* __restrict__ attn_b_out,
  const float* __restrict__ gate_w, const float* __restrict__ gate_b,
  const float* __restrict__ out_w, const float* __restrict__ out_b,
  float* __restrict__ out)
{
  const int a = blockIdx.x, t = threadIdx.x;
  __shared__ float att_s[128], upd_s[128], tmp_s[128];
  att_s[t] = att[a*128+t];
  upd_s[t] = upd[a*128+t];
  __syncthreads();
  float a2 = attn_b_out[t];
  for (int k=0;k<128;k++) a2 += att_s[k]*attn_w_out[t*128+k];
  float g = gate_b[t];
  for (int k=0;k<128;k++) g += upd_s[k]*gate_w[k*128+t];
  g = sigmoid_f(g);
  tmp_s[t] = g*a2 + (1.f-g)*upd_s[t];
  __syncthreads();
  float o = out_b[t];
  for (int k=0;k<128;k++) o += tmp_s[k]*out_w[k*128+t];
  out[a*128+t] = o;
}

extern "C" void kernel_launch(void* const* d_in, const int* in_sizes, int n_in,
                              void* d_out, int out_size, void* d_ws, size_t ws_size,
                              hipStream_t stream){
  const int*   atomic_numbers = (const int*)  d_in[0];
  const int*   edge_index     = (const int*)  d_in[2];
  const float* edge_vectors   = (const float*)d_in[3];
  const float* edge_lengths   = (const float*)d_in[4];
  const float* atom_embed     = (const float*)d_in[5];
  const float* rad_w1 = (const float*)d_in[6];
  const float* rad_b1 = (const float*)d_in[7];
  const float* rad_w2 = (const float*)d_in[8];
  const float* rad_b2 = (const float*)d_in[9];
  const float* tp_w   = (const float*)d_in[10];
  const float* tp_b   = (const float*)d_in[11];
  const float* msg_w1 = (const float*)d_in[12];
  const float* msg_b1 = (const float*)d_in[13];
  const float* msg_w2 = (const float*)d_in[14];
  const float* msg_b2 = (const float*)d_in[15];
  const float* attn_w_in  = (const float*)d_in[16];
  const float* attn_b_in  = (const float*)d_in[17];
  const float* attn_w_out = (const float*)d_in[18];
  const float* attn_b_out = (const float*)d_in[19];
  const float* gate_w = (const float*)d_in[20];
  const float* gate_b = (const float*)d_in[21];
  const float* out_w  = (const float*)d_in[22];
  const float* out_b  = (const float*)d_in[23];

  // workspace layout (no overlaps; offsets needs 4097 ints = 16388 B)
  char* ws = (char*)d_ws;
  int* counts    = (int*)(ws + 0);         // [0,      16384)
  int* cursor    = (int*)(ws + 16384);     // [16384,  32768)
  int* offsets   = (int*)(ws + 32768);     // [32768,  49156)
  int* edge_list = (int*)(ws + 53248);     // [53248,  577536)
  float* upd     = (float*)(ws + 577536);  // [577536, 2674688)
  float* qkv     = (float*)(ws + 2674688); // [2674688,8966144)
  float* att     = (float*)(ws + 8966144); // [8966144,11063296)

  hipMemsetAsync(ws, 0, 32768, stream);  // counts + cursor
  hist_kernel<<<(N_EDGES+255)/256, 256, 0, stream>>>(edge_index, counts);
  scan_kernel<<<1, 1024, 0, stream>>>(counts, offsets);
  scatter_kernel<<<(N_EDGES+255)/256, 256, 0, stream>>>(edge_index, offsets, cursor, edge_list);
  atom_kernel<<<N_ATOMS, 128, 0, stream>>>(atomic_numbers, atom_embed, edge_vectors, edge_lengths,
      rad_w1, rad_b1, rad_w2, rad_b2, tp_w, tp_b, msg_w1, msg_b1, msg_w2, msg_b2,
      attn_w_in, attn_b_in, offsets, edge_list, upd, qkv);
  attn_kernel<<<512, 256, 0, stream>>>(qkv, att);
  final_kernel<<<N_ATOMS, 128, 0, stream>>>(att, upd, attn_w_out, attn_b_out,
      gate_w, gate_b, out_w, out_b, (float*)d_out);
}

// Round 4
// 923.647 us; speedup vs baseline: 1.0992x; 1.0992x over previous
//
#include <hip/hip_runtime.h>
#include <math.h>

#define N_ATOMS 4096
#define N_EDGES 131072
#define PI6 0.52359877559829887f

__device__ __forceinline__ float silu_f(float x){ return x / (1.f + __expf(-x)); }
__device__ __forceinline__ float sigmoid_f(float x){ return 1.f / (1.f + __expf(-x)); }

// ---------- transpose attn_w_in (384x128) and attn_w_out (128x128) ----------
__global__ __launch_bounds__(256) void transpose_kernel(
  const float* __restrict__ win, const float* __restrict__ wout,
  float* __restrict__ wt_in, float* __restrict__ wt_out){
  int idx = blockIdx.x*256 + threadIdx.x;
  if (idx < 384*128){ int i = idx>>7, k = idx&127; wt_in[k*384+i] = win[idx]; }
  else { int j = idx - 384*128; int i = j>>7, k = j&127; wt_out[k*128+i] = wout[j]; }
}

// ---------- counting sort of edges by destination ----------
__global__ void hist_kernel(const int* __restrict__ edge_index, int* __restrict__ counts){
  int e = blockIdx.x*blockDim.x + threadIdx.x;
  if (e < N_EDGES) atomicAdd(&counts[edge_index[N_EDGES + e]], 1);
}

__global__ void scan_kernel(const int* __restrict__ counts, int* __restrict__ offsets){
  __shared__ int buf[4096];
  int t = threadIdx.x; // 1024 threads
  for (int i=t;i<4096;i+=1024) buf[i]=counts[i];
  __syncthreads();
  for (int off=1; off<4096; off<<=1){
    int v[4];
    #pragma unroll
    for (int k=0;k<4;k++){ int i=t+k*1024; v[k] = (i>=off)?buf[i-off]:0; }
    __syncthreads();
    #pragma unroll
    for (int k=0;k<4;k++){ int i=t+k*1024; buf[i]+=v[k]; }
    __syncthreads();
  }
  for (int i=t;i<4096;i+=1024) offsets[i]=buf[i]-counts[i]; // exclusive
  if (t==0) offsets[4096]=buf[4095];
}

__global__ void scatter_kernel(const int* __restrict__ edge_index, const int* __restrict__ offsets,
                               int* __restrict__ cursor, int* __restrict__ edge_list){
  int e = blockIdx.x*blockDim.x + threadIdx.x;
  if (e < N_EDGES){
    int d = edge_index[N_EDGES + e];
    int pos = atomicAdd(&cursor[d], 1);
    edge_list[offsets[d] + pos] = e;
  }
}

// ---------- per-atom edge features -> F (planar [9][N_ATOMS*128]) ----------
// w2 column in VGPRs; rad1 broadcast via shuffles; no LDS, no barriers.
__global__ __launch_bounds__(128) void edge_F_kernel(
  const float* __restrict__ edge_vectors, const float* __restrict__ edge_lengths,
  const float* __restrict__ rad_w1, const float* __restrict__ rad_b1,
  const float* __restrict__ rad_w2, const float* __restrict__ rad_b2,
  const int* __restrict__ offsets, const int* __restrict__ edge_list,
  float* __restrict__ Fp)
{
  const int a = blockIdx.x, t = threadIdx.x, lane = t & 63;
  float w2c[64], w1r[8];
  #pragma unroll
  for (int k=0;k<64;k++) w2c[k] = rad_w2[k*128 + t];
  #pragma unroll
  for (int k=0;k<8;k++)  w1r[k] = rad_w1[k*64 + lane];
  const float b1l = rad_b1[lane], b2c = rad_b2[t];
  float F9[9];
  #pragma unroll
  for (int j=0;j<9;j++) F9[j]=0.f;

  const int beg = offsets[a], end = offsets[a+1];
  for (int ei=beg; ei<end; ++ei){
    int e = edge_list[ei];
    e = __builtin_amdgcn_readfirstlane(e);
    float vx = edge_vectors[e*3], vy = edge_vectors[e*3+1], vz = edge_vectors[e*3+2];
    float d  = edge_lengths[e];
    float rn = sqrtf(vx*vx+vy*vy+vz*vz) + 1e-8f;
    float x = vx/rn, y = vy/rn, z = vz/rn;
    float sh[9] = {1.f, y, z, x, 3.f*z*z-1.f, x*z, y*z, x*y, x*x-y*y};
    float rb = 0.f;
    if (lane < 8){
      float cut = 0.5f*(__cosf(d*PI6)+1.f)*(d<6.f?1.f:0.f);
      rb = __sinf(d*((float)(lane+1)*PI6))/d*cut;
    }
    float pre = b1l;
    #pragma unroll
    for (int k=0;k<8;k++) pre += __shfl(rb, k, 64)*w1r[k];
    float r1 = silu_f(pre);
    float r2 = b2c;
    #pragma unroll
    for (int k=0;k<64;k++) r2 += __shfl(r1, k, 64)*w2c[k];
    r2 = silu_f(r2);
    #pragma unroll
    for (int j=0;j<9;j++) F9[j] += r2*sh[j];
  }
  #pragma unroll
  for (int j=0;j<9;j++) Fp[j*(N_ATOMS*128) + a*128 + t] = F9[j];
}

// ---------- node update: agg -> msg MLP -> qkv ; 8 atoms per 128-thr block ----------
__global__ __launch_bounds__(128) void node_kernel(
  const int* __restrict__ atomic_numbers, const float* __restrict__ atom_embed,
  const float* __restrict__ tp_w, const float* __restrict__ tp_b,
  const float* __restrict__ msg_w1, const float* __restrict__ msg_b1,
  const float* __restrict__ msg_w2, const float* __restrict__ msg_b2,
  const float* __restrict__ wt_in, const float* __restrict__ attn_b_in,
  const int* __restrict__ offsets, const float* __restrict__ Fp,
  float* __restrict__ upd_out, float* __restrict__ qkv_out)
{
  const int a0 = blockIdx.x*8, o = threadIdx.x;
  __shared__ float combs[8][192];
  __shared__ float hids[8][128];
  __shared__ float upds[8][128];

  float acc[8];
  const float tb = tp_b[o];
  #pragma unroll
  for (int a8=0;a8<8;a8++) acc[a8] = tb * (float)(offsets[a0+a8+1]-offsets[a0+a8]);
  for (int i=o;i<512;i+=128){ int a8=i>>6, k=i&63; combs[a8][k]=atom_embed[atomic_numbers[a0+a8]*64+k]; }

  const float4* Fp4 = (const float4*)Fp;
  for (int c4=0;c4<32;c4++){
    #pragma unroll
    for (int j=0;j<9;j++){
      float4 f[8];
      #pragma unroll
      for (int a8=0;a8<8;a8++) f[a8] = Fp4[j*(N_ATOMS*32) + (a0+a8)*32 + c4];
      #pragma unroll
      for (int cc=0;cc<4;cc++){
        int c = c4*4+cc;
        int row = (j==0)? c : (j<4 ? 128 + c*3 + (j-1) : 512 + c*5 + (j-4));
        float w = tp_w[row*128+o];
        #pragma unroll
        for (int a8=0;a8<8;a8++){
          float fv = (cc==0)?f[a8].x:(cc==1)?f[a8].y:(cc==2)?f[a8].z:f[a8].w;
          acc[a8] += fv*w;
        }
      }
    }
  }
  #pragma unroll
  for (int a8=0;a8<8;a8++) combs[a8][64+o] = acc[a8];
  __syncthreads();

  float h[8];
  const float mb1 = msg_b1[o];
  #pragma unroll
  for (int a8=0;a8<8;a8++) h[a8]=mb1;
  for (int k=0;k<192;k++){
    float w = msg_w1[k*128+o];
    #pragma unroll
    for (int a8=0;a8<8;a8++) h[a8] += combs[a8][k]*w;
  }
  #pragma unroll
  for (int a8=0;a8<8;a8++) hids[a8][o] = silu_f(h[a8]);
  __syncthreads();

  float u[8];
  const float mb2 = msg_b2[o];
  #pragma unroll
  for (int a8=0;a8<8;a8++) u[a8]=mb2;
  for (int k=0;k<128;k++){
    float w = msg_w2[k*128+o];
    #pragma unroll
    for (int a8=0;a8<8;a8++) u[a8] += hids[a8][k]*w;
  }
  #pragma unroll
  for (int a8=0;a8<8;a8++){ upds[a8][o]=u[a8]; upd_out[(a0+a8)*128+o]=u[a8]; }
  __syncthreads();

  for (int p=0;p<3;p++){
    float q[8];
    const float qb0 = attn_b_in[p*128+o];
    #pragma unroll
    for (int a8=0;a8<8;a8++) q[a8]=qb0;
    for (int k=0;k<128;k++){
      float w = wt_in[k*384 + p*128 + o];
      #pragma unroll
      for (int a8=0;a8<8;a8++) q[a8] += upds[a8][k]*w;
    }
    #pragma unroll
    for (int a8=0;a8<8;a8++) qkv_out[(a0+a8)*384 + p*128 + o] = q[a8];
  }
}

// ---------- flash attention: 4 heads, N=4096, D=32; 2 queries/thread ----------
__global__ __launch_bounds__(256) void attn_kernel(const float* __restrict__ qkv, float* __restrict__ att){
  const int b  = blockIdx.x;
  const int h  = b >> 6;    // 4 heads
  const int qb = b & 63;    // 64 query tiles of 64
  const int t  = threadIdx.x;
  const int q2 = t >> 3, s = t & 7;
  const int n0 = qb*64 + q2, n1 = n0 + 32;

  __shared__ float Ks[64*36];
  __shared__ float Vs[64*36];

  const float scale = 0.17677669529663687f; // 1/sqrt(32)
  float qv0[32], qv1[32];
  #pragma unroll
  for (int d=0; d<32; d++){
    qv0[d] = qkv[n0*384 + h*32 + d]*scale;
    qv1[d] = qkv[n1*384 + h*32 + d]*scale;
  }
  float mx0=-3e38f, su0=0.f, mx1=-3e38f, su1=0.f;
  float acc0[32], acc1[32];
  #pragma unroll
  for (int d=0; d<32; d++){ acc0[d]=0.f; acc1[d]=0.f; }

  for (int kt=0; kt<64; kt++){
    __syncthreads();
    for (int idx=t; idx<2048; idx+=256){
      int m = idx>>5, d = idx&31;
      Ks[m*36+d] = qkv[(kt*64+m)*384 + 128 + h*32 + d];
      Vs[m*36+d] = qkv[(kt*64+m)*384 + 256 + h*32 + d];
    }
    __syncthreads();
    for (int mm=0; mm<8; mm++){
      int m = mm*8 + s;
      float dot0=0.f, dot1=0.f;
      #pragma unroll
      for (int d=0; d<32; d++){ float kk = Ks[m*36+d]; dot0 += qv0[d]*kk; dot1 += qv1[d]*kk; }
      if (dot0 <= mx0){
        float p = __expf(dot0-mx0); su0 += p;
        #pragma unroll
        for (int d=0; d<32; d++) acc0[d] += p*Vs[m*36+d];
      } else {
        float c = __expf(mx0-dot0); su0 = su0*c + 1.f;
        #pragma unroll
        for (int d=0; d<32; d++) acc0[d] = acc0[d]*c + Vs[m*36+d];
        mx0 = dot0;
      }
      if (dot1 <= mx1){
        float p = __expf(dot1-mx1); su1 += p;
        #pragma unroll
        for (int d=0; d<32; d++) acc1[d] += p*Vs[m*36+d];
      } else {
        float c = __expf(mx1-dot1); su1 = su1*c + 1.f;
        #pragma unroll
        for (int d=0; d<32; d++) acc1[d] = acc1[d]*c + Vs[m*36+d];
        mx1 = dot1;
      }
    }
  }

  // merge the 8 key-slices (lanes within 8-groups of the same wave)
  #pragma unroll
  for (int off=1; off<8; off<<=1){
    float mo0 = __shfl_xor(mx0, off, 64), so0 = __shfl_xor(su0, off, 64);
    float M0 = fmaxf(mx0, mo0);
    float c10 = __expf(mx0-M0), c20 = __expf(mo0-M0);
    su0 = su0*c10 + so0*c20;
    float mo1 = __shfl_xor(mx1, off, 64), so1 = __shfl_xor(su1, off, 64);
    float M1 = fmaxf(mx1, mo1);
    float c11 = __expf(mx1-M1), c21 = __expf(mo1-M1);
    su1 = su1*c11 + so1*c21;
    #pragma unroll
    for (int d=0; d<32; d++){
      float ao0 = __shfl_xor(acc0[d], off, 64);
      acc0[d] = acc0[d]*c10 + ao0*c20;
      float ao1 = __shfl_xor(acc1[d], off, 64);
      acc1[d] = acc1[d]*c11 + ao1*c21;
    }
    mx0 = M0; mx1 = M1;
  }
  if (s == 0){
    float inv0 = 1.f/su0, inv1 = 1.f/su1;
    #pragma unroll
    for (int d=0; d<32; d++){
      att[n0*128 + h*32 + d] = acc0[d]*inv0;
      att[n1*128 + h*32 + d] = acc1[d]*inv1;
    }
  }
}

// ---------- epilogue: attn out proj, gate, final proj ; 8 atoms/block ----------
__global__ __launch_bounds__(128) void final_kernel(
  const float* __restrict__ att, const float* __restrict__ upd,
  const float* __restrict__ wt_out, const float* __restrict__ attn_b_out,
  const float* __restrict__ gate_w, const float* __restrict__ gate_b,
  const float* __restrict__ out_w, const float* __restrict__ out_b,
  float* __restrict__ out)
{
  const int a0 = blockIdx.x*8, o = threadIdx.x;
  __shared__ float tmps[8][128];
  float a2[8], g8[8];
  const float ab = attn_b_out[o], gb = gate_b[o];
  #pragma unroll
  for (int a8=0;a8<8;a8++){ a2[a8]=ab; g8[a8]=gb; }
  for (int k=0;k<128;k++){
    float wa = wt_out[k*128+o];
    float wg = gate_w[k*128+o];
    #pragma unroll
    for (int a8=0;a8<8;a8++){
      a2[a8] += att[(a0+a8)*128+k]*wa;
      g8[a8] += upd[(a0+a8)*128+k]*wg;
    }
  }
  #pragma unroll
  for (int a8=0;a8<8;a8++){
    float g = sigmoid_f(g8[a8]);
    float uo = upd[(a0+a8)*128+o];
    tmps[a8][o] = g*a2[a8] + (1.f-g)*uo;
  }
  __syncthreads();
  float ou[8];
  const float ob = out_b[o];
  #pragma unroll
  for (int a8=0;a8<8;a8++) ou[a8]=ob;
  for (int k=0;k<128;k++){
    float w = out_w[k*128+o];
    #pragma unroll
    for (int a8=0;a8<8;a8++) ou[a8] += tmps[a8][k]*w;
  }
  #pragma unroll
  for (int a8=0;a8<8;a8++) out[(a0+a8)*128+o] = ou[a8];
}

extern "C" void kernel_launch(void* const* d_in, const int* in_sizes, int n_in,
                              void* d_out, int out_size, void* d_ws, size_t ws_size,
                              hipStream_t stream){
  const int*   atomic_numbers = (const int*)  d_in[0];
  const int*   edge_index     = (const int*)  d_in[2];
  const float* edge_vectors   = (const float*)d_in[3];
  const float* edge_lengths   = (const float*)d_in[4];
  const float* atom_embed     = (const float*)d_in[5];
  const float* rad_w1 = (const float*)d_in[6];
  const float* rad_b1 = (const float*)d_in[7];
  const float* rad_w2 = (const float*)d_in[8];
  const float* rad_b2 = (const float*)d_in[9];
  const float* tp_w   = (const float*)d_in[10];
  const float* tp_b   = (const float*)d_in[11];
  const float* msg_w1 = (const float*)d_in[12];
  const float* msg_b1 = (const float*)d_in[13];
  const float* msg_w2 = (const float*)d_in[14];
  const float* msg_b2 = (const float*)d_in[15];
  const float* attn_w_in  = (const float*)d_in[16];
  const float* attn_b_in  = (const float*)d_in[17];
  const float* attn_w_out = (const float*)d_in[18];
  const float* attn_b_out = (const float*)d_in[19];
  const float* gate_w = (const float*)d_in[20];
  const float* gate_b = (const float*)d_in[21];
  const float* out_w  = (const float*)d_in[22];
  const float* out_b  = (const float*)d_in[23];

  // workspace layout (bytes)
  char* ws = (char*)d_ws;
  int* counts    = (int*)(ws);             // [0, 16384)
  int* cursor    = (int*)(ws + 16384);     // [16384, 32768)
  int* offsets   = (int*)(ws + 32768);     // [32768, 49156)  4097 ints
  int* edge_list = (int*)(ws + 53248);     // [53248, 577536)
  float* wt_in   = (float*)(ws + 577536);  // 128x384 = 196608 B
  float* wt_out  = (float*)(ws + 774144);  // 128x128 = 65536 B
  float* Fp      = (float*)(ws + 839680);  // [9][4096*128] = 18.9 MB
  float* att     = (float*)(ws + 839680);  // aliases Fp plane 0 (Fp dead before attn)
  float* upd     = (float*)(ws + 19714048);// 2 MB
  float* qkv     = (float*)(ws + 21811200);// 6.3 MB  (end 28102656)

  transpose_kernel<<<256, 256, 0, stream>>>(attn_w_in, attn_w_out, wt_in, wt_out);
  hipMemsetAsync(ws, 0, 32768, stream);  // counts + cursor
  hist_kernel<<<(N_EDGES+255)/256, 256, 0, stream>>>(edge_index, counts);
  scan_kernel<<<1, 1024, 0, stream>>>(counts, offsets);
  scatter_kernel<<<(N_EDGES+255)/256, 256, 0, stream>>>(edge_index, offsets, cursor, edge_list);
  edge_F_kernel<<<N_ATOMS, 128, 0, stream>>>(edge_vectors, edge_lengths,
      rad_w1, rad_b1, rad_w2, rad_b2, offsets, edge_list, Fp);
  node_kernel<<<N_ATOMS/8, 128, 0, stream>>>(atomic_numbers, atom_embed,
      tp_w, tp_b, msg_w1, msg_b1, msg_w2, msg_b2, wt_in, attn_b_in,
      offsets, Fp, upd, qkv);
  attn_kernel<<<256, 256, 0, stream>>>(qkv, att);
  final_kernel<<<N_ATOMS/8, 128, 0, stream>>>(att, upd, wt_out, attn_b_out,
      gate_w, gate_b, out_w, out_b, (float*)d_out);
}

// Round 5
// 610.792 us; speedup vs baseline: 1.6623x; 1.5122x over previous
//
#include <hip/hip_runtime.h>
#include <math.h>

#define N_ATOMS 4096
#define N_EDGES 131072
#define PI6 0.52359877559829887f

__device__ __forceinline__ float silu_f(float x){ return x / (1.f + __expf(-x)); }
__device__ __forceinline__ float sigmoid_f(float x){ return 1.f / (1.f + __expf(-x)); }

// ---------- transpose attn_w_in (384x128) and attn_w_out (128x128) ----------
__global__ __launch_bounds__(256) void transpose_kernel(
  const float* __restrict__ win, const float* __restrict__ wout,
  float* __restrict__ wt_in, float* __restrict__ wt_out){
  int idx = blockIdx.x*256 + threadIdx.x;
  if (idx < 384*128){ int i = idx>>7, k = idx&127; wt_in[k*384+i] = win[idx]; }
  else { int j = idx - 384*128; int i = j>>7, k = j&127; wt_out[k*128+i] = wout[j]; }
}

// ---------- counting sort of edges by destination ----------
__global__ void hist_kernel(const int* __restrict__ edge_index, int* __restrict__ counts){
  int e = blockIdx.x*blockDim.x + threadIdx.x;
  if (e < N_EDGES) atomicAdd(&counts[edge_index[N_EDGES + e]], 1);
}

__global__ void scan_kernel(const int* __restrict__ counts, int* __restrict__ offsets){
  __shared__ int buf[4096];
  int t = threadIdx.x; // 1024 threads
  for (int i=t;i<4096;i+=1024) buf[i]=counts[i];
  __syncthreads();
  for (int off=1; off<4096; off<<=1){
    int v[4];
    #pragma unroll
    for (int k=0;k<4;k++){ int i=t+k*1024; v[k] = (i>=off)?buf[i-off]:0; }
    __syncthreads();
    #pragma unroll
    for (int k=0;k<4;k++){ int i=t+k*1024; buf[i]+=v[k]; }
    __syncthreads();
  }
  for (int i=t;i<4096;i+=1024) offsets[i]=buf[i]-counts[i]; // exclusive
  if (t==0) offsets[4096]=buf[4095];
}

__global__ void scatter_kernel(const int* __restrict__ edge_index, const int* __restrict__ offsets,
                               int* __restrict__ cursor, int* __restrict__ edge_list){
  int e = blockIdx.x*blockDim.x + threadIdx.x;
  if (e < N_EDGES){
    int d = edge_index[N_EDGES + e];
    int pos = atomicAdd(&cursor[d], 1);
    edge_list[offsets[d] + pos] = e;
  }
}

// ---------- per-atom edge features -> F (planar [9][N_ATOMS*128]) ----------
__global__ __launch_bounds__(128) void edge_F_kernel(
  const float* __restrict__ edge_vectors, const float* __restrict__ edge_lengths,
  const float* __restrict__ rad_w1, const float* __restrict__ rad_b1,
  const float* __restrict__ rad_w2, const float* __restrict__ rad_b2,
  const int* __restrict__ offsets, const int* __restrict__ edge_list,
  float* __restrict__ Fp)
{
  const int a = blockIdx.x, t = threadIdx.x, lane = t & 63;
  float w2c[64], w1r[8];
  #pragma unroll
  for (int k=0;k<64;k++) w2c[k] = rad_w2[k*128 + t];
  #pragma unroll
  for (int k=0;k<8;k++)  w1r[k] = rad_w1[k*64 + lane];
  const float b1l = rad_b1[lane], b2c = rad_b2[t];
  float F9[9];
  #pragma unroll
  for (int j=0;j<9;j++) F9[j]=0.f;

  const int beg = offsets[a], end = offsets[a+1];
  for (int ei=beg; ei<end; ++ei){
    int e = edge_list[ei];
    e = __builtin_amdgcn_readfirstlane(e);
    float vx = edge_vectors[e*3], vy = edge_vectors[e*3+1], vz = edge_vectors[e*3+2];
    float d  = edge_lengths[e];
    float rn = sqrtf(vx*vx+vy*vy+vz*vz) + 1e-8f;
    float x = vx/rn, y = vy/rn, z = vz/rn;
    float sh[9] = {1.f, y, z, x, 3.f*z*z-1.f, x*z, y*z, x*y, x*x-y*y};
    float rb = 0.f;
    if (lane < 8){
      float cut = 0.5f*(__cosf(d*PI6)+1.f)*(d<6.f?1.f:0.f);
      rb = __sinf(d*((float)(lane+1)*PI6))/d*cut;
    }
    float pre = b1l;
    #pragma unroll
    for (int k=0;k<8;k++) pre += __shfl(rb, k, 64)*w1r[k];
    float r1 = silu_f(pre);
    float r2 = b2c;
    #pragma unroll
    for (int k=0;k<64;k++) r2 += __shfl(r1, k, 64)*w2c[k];
    r2 = silu_f(r2);
    #pragma unroll
    for (int j=0;j<9;j++) F9[j] += r2*sh[j];
  }
  #pragma unroll
  for (int j=0;j<9;j++) Fp[j*(N_ATOMS*128) + a*128 + t] = F9[j];
}

// ---------- node update: agg -> msg MLP -> qkv ; 8 atoms, 512 threads ----------
__global__ __launch_bounds__(512) void node_kernel(
  const int* __restrict__ atomic_numbers, const float* __restrict__ atom_embed,
  const float* __restrict__ tp_w, const float* __restrict__ tp_b,
  const float* __restrict__ msg_w1, const float* __restrict__ msg_b1,
  const float* __restrict__ msg_w2, const float* __restrict__ msg_b2,
  const float* __restrict__ wt_in, const float* __restrict__ attn_b_in,
  const int* __restrict__ offsets, const float* __restrict__ Fp,
  float* __restrict__ upd_out, float* __restrict__ qkv_out)
{
  const int a0 = blockIdx.x*8, tid = threadIdx.x;
  const int g = tid >> 7, o = tid & 127;
  __shared__ float red[4][8][128];   // 16 KB
  __shared__ float combs[8][192];
  __shared__ float hids[8][128];
  __shared__ float upds[8][128];

  float acc[8];
  #pragma unroll
  for (int a8=0;a8<8;a8++) acc[a8] = 0.f;

  const float4* Fp4 = (const float4*)Fp;
  for (int c4=g*8; c4<g*8+8; c4++){
    #pragma unroll
    for (int j=0;j<9;j++){
      float4 f[8];
      #pragma unroll
      for (int a8=0;a8<8;a8++) f[a8] = Fp4[j*(N_ATOMS*32) + (a0+a8)*32 + c4];
      #pragma unroll
      for (int cc=0;cc<4;cc++){
        int c = c4*4+cc;
        int row = (j==0)? c : (j<4 ? 128 + c*3 + (j-1) : 512 + c*5 + (j-4));
        float w = tp_w[row*128+o];
        #pragma unroll
        for (int a8=0;a8<8;a8++){
          float fv = (cc==0)?f[a8].x:(cc==1)?f[a8].y:(cc==2)?f[a8].z:f[a8].w;
          acc[a8] += fv*w;
        }
      }
    }
  }
  #pragma unroll
  for (int a8=0;a8<8;a8++) red[g][a8][o] = acc[a8];
  { int a8 = tid>>6, k = tid&63;
    combs[a8][k] = atom_embed[atomic_numbers[a0+a8]*64 + k]; }
  __syncthreads();
  if (g==0){
    const float tb = tp_b[o];
    #pragma unroll
    for (int a8=0;a8<8;a8++){
      float deg = (float)(offsets[a0+a8+1]-offsets[a0+a8]);
      combs[a8][64+o] = red[0][a8][o]+red[1][a8][o]+red[2][a8][o]+red[3][a8][o] + tb*deg;
    }
  }
  __syncthreads();

  const int aA = 2*g, aB = 2*g+1;
  {
    float hA = msg_b1[o], hB = hA;
    for (int k=0;k<192;k++){
      float w = msg_w1[k*128+o];
      hA += combs[aA][k]*w; hB += combs[aB][k]*w;
    }
    hids[aA][o] = silu_f(hA); hids[aB][o] = silu_f(hB);
  }
  __syncthreads();
  {
    float uA = msg_b2[o], uB = uA;
    for (int k=0;k<128;k++){
      float w = msg_w2[k*128+o];
      uA += hids[aA][k]*w; uB += hids[aB][k]*w;
    }
    upds[aA][o]=uA; upds[aB][o]=uB;
    upd_out[(a0+aA)*128+o]=uA; upd_out[(a0+aB)*128+o]=uB;
  }
  __syncthreads();
  for (int p=0;p<3;p++){
    float qA = attn_b_in[p*128+o], qB = qA;
    for (int k=0;k<128;k++){
      float w = wt_in[k*384 + p*128 + o];
      qA += upds[aA][k]*w; qB += upds[aB][k]*w;
    }
    qkv_out[(a0+aA)*384 + p*128 + o] = qA;
    qkv_out[(a0+aB)*384 + p*128 + o] = qB;
  }
}

// ---------- flash attention: 1024 thr, 1 query/thread, 16 key-slices ----------
__global__ __launch_bounds__(1024) void attn_kernel(const float* __restrict__ qkv, float* __restrict__ att){
  const int b  = blockIdx.x;
  const int h  = b >> 6;    // 4 heads
  const int qb = b & 63;    // 64 query tiles of 64
  const int t  = threadIdx.x;
  const int q  = t >> 4, s = t & 15;
  const int n  = qb*64 + q;

  __shared__ float Ks[128*36];  // 18 KB
  __shared__ float Vs[128*36];  // 18 KB

  const float scale = 0.17677669529663687f; // 1/sqrt(32)
  float qv[32];
  #pragma unroll
  for (int d=0; d<32; d++) qv[d] = qkv[n*384 + h*32 + d]*scale;

  float mx=-3e38f, su=0.f;
  float acc[32];
  #pragma unroll
  for (int d=0; d<32; d++) acc[d]=0.f;

  for (int kt=0; kt<32; kt++){
    __syncthreads();
    for (int idx=t; idx<4096; idx+=1024){
      int m = idx>>5, d = idx&31;
      Ks[m*36+d] = qkv[(kt*128+m)*384 + 128 + h*32 + d];
      Vs[m*36+d] = qkv[(kt*128+m)*384 + 256 + h*32 + d];
    }
    __syncthreads();
    #pragma unroll
    for (int i=0;i<8;i++){
      int m = s + i*16;
      float dot = 0.f;
      #pragma unroll
      for (int d=0; d<32; d++) dot += qv[d]*Ks[m*36+d];
      if (dot <= mx){
        float p = __expf(dot-mx); su += p;
        #pragma unroll
        for (int d=0; d<32; d++) acc[d] += p*Vs[m*36+d];
      } else {
        float c = __expf(mx-dot); su = su*c + 1.f;
        #pragma unroll
        for (int d=0; d<32; d++) acc[d] = acc[d]*c + Vs[m*36+d];
        mx = dot;
      }
    }
  }

  // merge the 16 key-slices (contiguous 16-lane groups within a wave)
  #pragma unroll
  for (int off=1; off<16; off<<=1){
    float mo = __shfl_xor(mx, off, 64), so = __shfl_xor(su, off, 64);
    float M  = fmaxf(mx, mo);
    float c1 = __expf(mx-M), c2 = __expf(mo-M);
    su = su*c1 + so*c2;
    #pragma unroll
    for (int d=0; d<32; d++){
      float ao = __shfl_xor(acc[d], off, 64);
      acc[d] = acc[d]*c1 + ao*c2;
    }
    mx = M;
  }
  if (s == 0){
    float inv = 1.f/su;
    #pragma unroll
    for (int d=0; d<32; d++) att[n*128 + h*32 + d] = acc[d]*inv;
  }
}

// ---------- epilogue: 8 atoms, 512 threads, LDS-staged operands ----------
__global__ __launch_bounds__(512) void final_kernel(
  const float* __restrict__ att, const float* __restrict__ upd,
  const float* __restrict__ wt_out, const float* __restrict__ attn_b_out,
  const float* __restrict__ gate_w, const float* __restrict__ gate_b,
  const float* __restrict__ out_w, const float* __restrict__ out_b,
  float* __restrict__ out)
{
  const int a0 = blockIdx.x*8, tid = threadIdx.x;
  const int g = tid >> 7, o = tid & 127;
  __shared__ float att_s[8][128], upd_s[8][128], tmps[8][128];
  for (int i=tid; i<1024; i+=512){
    int a8 = i>>7, k = i&127;
    att_s[a8][k] = att[(a0+a8)*128+k];
    upd_s[a8][k] = upd[(a0+a8)*128+k];
  }
  __syncthreads();
  const int aA = 2*g, aB = 2*g+1;
  float a2A = attn_b_out[o], a2B = a2A;
  float gA = gate_b[o], gB = gA;
  for (int k=0;k<128;k++){
    float wa = wt_out[k*128+o];
    float wg = gate_w[k*128+o];
    a2A += att_s[aA][k]*wa; a2B += att_s[aB][k]*wa;
    gA  += upd_s[aA][k]*wg; gB  += upd_s[aB][k]*wg;
  }
  gA = sigmoid_f(gA); gB = sigmoid_f(gB);
  tmps[aA][o] = gA*a2A + (1.f-gA)*upd_s[aA][o];
  tmps[aB][o] = gB*a2B + (1.f-gB)*upd_s[aB][o];
  __syncthreads();
  float ouA = out_b[o], ouB = ouA;
  for (int k=0;k<128;k++){
    float w = out_w[k*128+o];
    ouA += tmps[aA][k]*w; ouB += tmps[aB][k]*w;
  }
  out[(a0+aA)*128+o] = ouA;
  out[(a0+aB)*128+o] = ouB;
}

extern "C" void kernel_launch(void* const* d_in, const int* in_sizes, int n_in,
                              void* d_out, int out_size, void* d_ws, size_t ws_size,
                              hipStream_t stream){
  const int*   atomic_numbers = (const int*)  d_in[0];
  const int*   edge_index     = (const int*)  d_in[2];
  const float* edge_vectors   = (const float*)d_in[3];
  const float* edge_lengths   = (const float*)d_in[4];
  const float* atom_embed     = (const float*)d_in[5];
  const float* rad_w1 = (const float*)d_in[6];
  const float* rad_b1 = (const float*)d_in[7];
  const float* rad_w2 = (const float*)d_in[8];
  const float* rad_b2 = (const float*)d_in[9];
  const float* tp_w   = (const float*)d_in[10];
  const float* tp_b   = (const float*)d_in[11];
  const float* msg_w1 = (const float*)d_in[12];
  const float* msg_b1 = (const float*)d_in[13];
  const float* msg_w2 = (const float*)d_in[14];
  const float* msg_b2 = (const float*)d_in[15];
  const float* attn_w_in  = (const float*)d_in[16];
  const float* attn_b_in  = (const float*)d_in[17];
  const float* attn_w_out = (const float*)d_in[18];
  const float* attn_b_out = (const float*)d_in[19];
  const float* gate_w = (const float*)d_in[20];
  const float* gate_b = (const float*)d_in[21];
  const float* out_w  = (const float*)d_in[22];
  const float* out_b  = (const float*)d_in[23];

  // workspace layout (bytes)
  char* ws = (char*)d_ws;
  int* counts    = (int*)(ws);             // [0, 16384)
  int* cursor    = (int*)(ws + 16384);     // [16384, 32768)
  int* offsets   = (int*)(ws + 32768);     // [32768, 49156)  4097 ints
  int* edge_list = (int*)(ws + 53248);     // [53248, 577536)
  float* wt_in   = (float*)(ws + 577536);  // 128x384
  float* wt_out  = (float*)(ws + 774144);  // 128x128
  float* Fp      = (float*)(ws + 839680);  // [9][4096*128] = 18.9 MB
  float* att     = (float*)(ws + 839680);  // aliases Fp plane 0 (Fp dead before attn)
  float* upd     = (float*)(ws + 19714048);// 2 MB
  float* qkv     = (float*)(ws + 21811200);// 6.3 MB  (end 28102656)

  transpose_kernel<<<256, 256, 0, stream>>>(attn_w_in, attn_w_out, wt_in, wt_out);
  hipMemsetAsync(ws, 0, 32768, stream);  // counts + cursor
  hist_kernel<<<(N_EDGES+255)/256, 256, 0, stream>>>(edge_index, counts);
  scan_kernel<<<1, 1024, 0, stream>>>(counts, offsets);
  scatter_kernel<<<(N_EDGES+255)/256, 256, 0, stream>>>(edge_index, offsets, cursor, edge_list);
  edge_F_kernel<<<N_ATOMS, 128, 0, stream>>>(edge_vectors, edge_lengths,
      rad_w1, rad_b1, rad_w2, rad_b2, offsets, edge_list, Fp);
  node_kernel<<<N_ATOMS/8, 512, 0, stream>>>(atomic_numbers, atom_embed,
      tp_w, tp_b, msg_w1, msg_b1, msg_w2, msg_b2, wt_in, attn_b_in,
      offsets, Fp, upd, qkv);
  attn_kernel<<<256, 1024, 0, stream>>>(qkv, att);
  final_kernel<<<N_ATOMS/8, 512, 0, stream>>>(att, upd, wt_out, attn_b_out,
      gate_w, gate_b, out_w, out_b, (float*)d_out);
}

// Round 6
// 539.796 us; speedup vs baseline: 1.8809x; 1.1315x over previous
//
#include <hip/hip_runtime.h>
#include <math.h>

#define N_ATOMS 4096
#define N_EDGES 131072
#define PI6 0.52359877559829887f

__device__ __forceinline__ float silu_f(float x){ return x / (1.f + __expf(-x)); }
__device__ __forceinline__ float sigmoid_f(float x){ return 1.f / (1.f + __expf(-x)); }
__device__ __forceinline__ float bcastf(float v, int k){
  return __int_as_float(__builtin_amdgcn_readlane(__float_as_int(v), k));
}

// ---------- transpose attn_w_in (384x128) and attn_w_out (128x128) ----------
__global__ __launch_bounds__(256) void transpose_kernel(
  const float* __restrict__ win, const float* __restrict__ wout,
  float* __restrict__ wt_in, float* __restrict__ wt_out){
  int idx = blockIdx.x*256 + threadIdx.x;
  if (idx < 384*128){ int i = idx>>7, k = idx&127; wt_in[k*384+i] = win[idx]; }
  else { int j = idx - 384*128; int i = j>>7, k = j&127; wt_out[k*128+i] = wout[j]; }
}

// ---------- counting sort of edges by destination ----------
__global__ void hist_kernel(const int* __restrict__ edge_index, int* __restrict__ counts){
  int e = blockIdx.x*blockDim.x + threadIdx.x;
  if (e < N_EDGES) atomicAdd(&counts[edge_index[N_EDGES + e]], 1);
}

__global__ void scan_kernel(const int* __restrict__ counts, int* __restrict__ offsets){
  __shared__ int buf[4096];
  int t = threadIdx.x; // 1024 threads
  for (int i=t;i<4096;i+=1024) buf[i]=counts[i];
  __syncthreads();
  for (int off=1; off<4096; off<<=1){
    int v[4];
    #pragma unroll
    for (int k=0;k<4;k++){ int i=t+k*1024; v[k] = (i>=off)?buf[i-off]:0; }
    __syncthreads();
    #pragma unroll
    for (int k=0;k<4;k++){ int i=t+k*1024; buf[i]+=v[k]; }
    __syncthreads();
  }
  for (int i=t;i<4096;i+=1024) offsets[i]=buf[i]-counts[i]; // exclusive
  if (t==0) offsets[4096]=buf[4095];
}

__global__ void scatter_kernel(const int* __restrict__ edge_index, const int* __restrict__ offsets,
                               int* __restrict__ cursor, int* __restrict__ edge_list){
  int e = blockIdx.x*blockDim.x + threadIdx.x;
  if (e < N_EDGES){
    int d = edge_index[N_EDGES + e];
    int pos = atomicAdd(&cursor[d], 1);
    edge_list[offsets[d] + pos] = e;
  }
}

// ---------- per-atom edge features -> F (planar [9][N_ATOMS*128]) ----------
// 512 thr = 4 edge-groups x 128 channels; readlane broadcasts (no LDS pipe).
__global__ __launch_bounds__(512) void edge_F_kernel(
  const float* __restrict__ edge_vectors, const float* __restrict__ edge_lengths,
  const float* __restrict__ rad_w1, const float* __restrict__ rad_b1,
  const float* __restrict__ rad_w2, const float* __restrict__ rad_b2,
  const int* __restrict__ offsets, const int* __restrict__ edge_list,
  float* __restrict__ Fp)
{
  const int a = blockIdx.x, tid = threadIdx.x;
  const int g = tid >> 7;        // edge group 0..3
  const int t = tid & 127;       // channel
  const int lane = tid & 63;
  __shared__ float Fred[4][128][9];   // 18 KB

  float w2c[64], w1r[8];
  #pragma unroll
  for (int k=0;k<64;k++) w2c[k] = rad_w2[k*128 + t];
  #pragma unroll
  for (int k=0;k<8;k++)  w1r[k] = rad_w1[k*64 + lane];
  const float b1l = rad_b1[lane], b2c = rad_b2[t];
  float F9[9];
  #pragma unroll
  for (int j=0;j<9;j++) F9[j]=0.f;

  const int beg = offsets[a], end = offsets[a+1];
  for (int ei=beg+g; ei<end; ei+=4){
    int e = __builtin_amdgcn_readfirstlane(edge_list[ei]);
    float vx = edge_vectors[e*3], vy = edge_vectors[e*3+1], vz = edge_vectors[e*3+2];
    float d  = edge_lengths[e];
    float rn = sqrtf(vx*vx+vy*vy+vz*vz) + 1e-8f;
    float x = vx/rn, y = vy/rn, z = vz/rn;
    float sh[9] = {1.f, y, z, x, 3.f*z*z-1.f, x*z, y*z, x*y, x*x-y*y};
    float rb = 0.f;
    if (lane < 8){
      float cut = 0.5f*(__cosf(d*PI6)+1.f)*(d<6.f?1.f:0.f);
      rb = __sinf(d*((float)(lane+1)*PI6))/d*cut;
    }
    float pa = b1l, pb = 0.f;
    #pragma unroll
    for (int k=0;k<8;k+=2){
      pa += bcastf(rb,k)*w1r[k];
      pb += bcastf(rb,k+1)*w1r[k+1];
    }
    float r1 = silu_f(pa+pb);
    float r2a=b2c, r2b=0.f, r2c=0.f, r2d=0.f;
    #pragma unroll
    for (int k=0;k<64;k+=4){
      r2a += bcastf(r1,k  )*w2c[k  ];
      r2b += bcastf(r1,k+1)*w2c[k+1];
      r2c += bcastf(r1,k+2)*w2c[k+2];
      r2d += bcastf(r1,k+3)*w2c[k+3];
    }
    float r2 = silu_f((r2a+r2b)+(r2c+r2d));
    #pragma unroll
    for (int j=0;j<9;j++) F9[j] += r2*sh[j];
  }

  #pragma unroll
  for (int j=0;j<9;j++) Fred[g][t][j] = F9[j];
  __syncthreads();
  if (g==0){
    #pragma unroll
    for (int j=0;j<9;j++)
      Fp[j*(N_ATOMS*128) + a*128 + t] = F9[j] + Fred[1][t][j] + Fred[2][t][j] + Fred[3][t][j];
  }
}

// ---------- node update: agg -> msg MLP -> qkv ; 8 atoms, 512 threads ----------
__global__ __launch_bounds__(512) void node_kernel(
  const int* __restrict__ atomic_numbers, const float* __restrict__ atom_embed,
  const float* __restrict__ tp_w, const float* __restrict__ tp_b,
  const float* __restrict__ msg_w1, const float* __restrict__ msg_b1,
  const float* __restrict__ msg_w2, const float* __restrict__ msg_b2,
  const float* __restrict__ wt_in, const float* __restrict__ attn_b_in,
  const int* __restrict__ offsets, const float* __restrict__ Fp,
  float* __restrict__ upd_out, float* __restrict__ qkv_out)
{
  const int a0 = blockIdx.x*8, tid = threadIdx.x;
  const int g = tid >> 7, o = tid & 127;
  __shared__ float red[4][8][128];   // 16 KB
  __shared__ float combs[8][192];
  __shared__ float hids[8][128];
  __shared__ float upds[8][128];

  float acc[8];
  #pragma unroll
  for (int a8=0;a8<8;a8++) acc[a8] = 0.f;

  const float4* Fp4 = (const float4*)Fp;
  for (int c4=g*8; c4<g*8+8; c4++){
    #pragma unroll
    for (int j=0;j<9;j++){
      float4 f[8];
      #pragma unroll
      for (int a8=0;a8<8;a8++) f[a8] = Fp4[j*(N_ATOMS*32) + (a0+a8)*32 + c4];
      #pragma unroll
      for (int cc=0;cc<4;cc++){
        int c = c4*4+cc;
        int row = (j==0)? c : (j<4 ? 128 + c*3 + (j-1) : 512 + c*5 + (j-4));
        float w = tp_w[row*128+o];
        #pragma unroll
        for (int a8=0;a8<8;a8++){
          float fv = (cc==0)?f[a8].x:(cc==1)?f[a8].y:(cc==2)?f[a8].z:f[a8].w;
          acc[a8] += fv*w;
        }
      }
    }
  }
  #pragma unroll
  for (int a8=0;a8<8;a8++) red[g][a8][o] = acc[a8];
  { int a8 = tid>>6, k = tid&63;
    combs[a8][k] = atom_embed[atomic_numbers[a0+a8]*64 + k]; }
  __syncthreads();
  if (g==0){
    const float tb = tp_b[o];
    #pragma unroll
    for (int a8=0;a8<8;a8++){
      float deg = (float)(offsets[a0+a8+1]-offsets[a0+a8]);
      combs[a8][64+o] = red[0][a8][o]+red[1][a8][o]+red[2][a8][o]+red[3][a8][o] + tb*deg;
    }
  }
  __syncthreads();

  const int aA = 2*g, aB = 2*g+1;
  {
    float hA = msg_b1[o], hB = hA;
    for (int k=0;k<192;k++){
      float w = msg_w1[k*128+o];
      hA += combs[aA][k]*w; hB += combs[aB][k]*w;
    }
    hids[aA][o] = silu_f(hA); hids[aB][o] = silu_f(hB);
  }
  __syncthreads();
  {
    float uA = msg_b2[o], uB = uA;
    for (int k=0;k<128;k++){
      float w = msg_w2[k*128+o];
      uA += hids[aA][k]*w; uB += hids[aB][k]*w;
    }
    upds[aA][o]=uA; upds[aB][o]=uB;
    upd_out[(a0+aA)*128+o]=uA; upd_out[(a0+aB)*128+o]=uB;
  }
  __syncthreads();
  for (int p=0;p<3;p++){
    float qA = attn_b_in[p*128+o], qB = qA;
    for (int k=0;k<128;k++){
      float w = wt_in[k*384 + p*128 + o];
      qA += upds[aA][k]*w; qB += upds[aB][k]*w;
    }
    qkv_out[(a0+aA)*384 + p*128 + o] = qA;
    qkv_out[(a0+aB)*384 + p*128 + o] = qB;
  }
}

// ---------- attention: lane=query, wave=key-slice; K/V rows via s_loads ----------
__global__ __launch_bounds__(1024) void attn_kernel(const float* __restrict__ qkv, float* __restrict__ att){
  const int b  = blockIdx.x;
  const int h  = b >> 6;     // 4 heads
  const int qt = b & 63;     // 64 query tiles of 64
  const int tid = threadIdx.x;
  const int w = tid >> 6;    // wave 0..15 = key slice
  const int lane = tid & 63; // query lane
  const int n = qt*64 + lane;

  __shared__ float MB[8][64][34];   // 69.6 KB merge buffer

  const float scale = 0.17677669529663687f; // 1/sqrt(32)
  float qv[32];
  #pragma unroll
  for (int d=0; d<32; d++) qv[d] = qkv[n*384 + h*32 + d]*scale;

  float mx=-3e38f, su=0.f;
  float acc[32];
  #pragma unroll
  for (int d=0; d<32; d++) acc[d]=0.f;

  const int m0 = w*256;
  for (int m=m0; m<m0+256; ++m){
    int mu = __builtin_amdgcn_readfirstlane(m);
    const float* kr = qkv + (size_t)mu*384 + 128 + h*32;  // wave-uniform -> s_load
    float d0=0.f,d1=0.f,d2=0.f,d3=0.f;
    #pragma unroll
    for (int d=0; d<32; d+=4){
      d0 += qv[d]*kr[d]; d1 += qv[d+1]*kr[d+1];
      d2 += qv[d+2]*kr[d+2]; d3 += qv[d+3]*kr[d+3];
    }
    float dot = (d0+d1)+(d2+d3);
    const float* vr = kr + 128;
    if (dot <= mx){
      float p = __expf(dot-mx); su += p;
      #pragma unroll
      for (int d=0; d<32; d++) acc[d] += p*vr[d];
    } else {
      float c = __expf(mx-dot); su = su*c + 1.f;
      #pragma unroll
      for (int d=0; d<32; d++) acc[d] = acc[d]*c + vr[d];
      mx = dot;
    }
  }

  // 16 -> 8 -> 4 -> 2 -> 1 merge tree via LDS
  #define STORE_P(dst) { MB[dst][lane][0]=mx; MB[dst][lane][1]=su; \
    _Pragma("unroll") for (int d=0;d<32;d++) MB[dst][lane][2+d]=acc[d]; }
  #define MERGE_P(src) { float mo=MB[src][lane][0], so=MB[src][lane][1]; \
    float M=fmaxf(mx,mo); float c1=__expf(mx-M), c2=__expf(mo-M); \
    su=su*c1+so*c2; \
    _Pragma("unroll") for (int d=0;d<32;d++) acc[d]=acc[d]*c1+MB[src][lane][2+d]*c2; \
    mx=M; }

  if (w>=8) STORE_P(w-8);
  __syncthreads();
  if (w<8)  MERGE_P(w);
  __syncthreads();
  if (w>=4 && w<8) STORE_P(w-4);
  __syncthreads();
  if (w<4)  MERGE_P(w);
  __syncthreads();
  if (w>=2 && w<4) STORE_P(w-2);
  __syncthreads();
  if (w<2)  MERGE_P(w);
  __syncthreads();
  if (w==1) STORE_P(0);
  __syncthreads();
  if (w==0){
    MERGE_P(0);
    float inv = 1.f/su;
    #pragma unroll
    for (int d=0; d<32; d++) att[n*128 + h*32 + d] = acc[d]*inv;
  }
}

// ---------- epilogue: 8 atoms, 512 threads, LDS-staged operands ----------
__global__ __launch_bounds__(512) void final_kernel(
  const float* __restrict__ att, const float* __restrict__ upd,
  const float* __restrict__ wt_out, const float* __restrict__ attn_b_out,
  const float* __restrict__ gate_w, const float* __restrict__ gate_b,
  const float* __restrict__ out_w, const float* __restrict__ out_b,
  float* __restrict__ out)
{
  const int a0 = blockIdx.x*8, tid = threadIdx.x;
  const int g = tid >> 7, o = tid & 127;
  __shared__ float att_s[8][128], upd_s[8][128], tmps[8][128];
  for (int i=tid; i<1024; i+=512){
    int a8 = i>>7, k = i&127;
    att_s[a8][k] = att[(a0+a8)*128+k];
    upd_s[a8][k] = upd[(a0+a8)*128+k];
  }
  __syncthreads();
  const int aA = 2*g, aB = 2*g+1;
  float a2A = attn_b_out[o], a2B = a2A;
  float gA = gate_b[o], gB = gA;
  for (int k=0;k<128;k++){
    float wa = wt_out[k*128+o];
    float wg = gate_w[k*128+o];
    a2A += att_s[aA][k]*wa; a2B += att_s[aB][k]*wa;
    gA  += upd_s[aA][k]*wg; gB  += upd_s[aB][k]*wg;
  }
  gA = sigmoid_f(gA); gB = sigmoid_f(gB);
  tmps[aA][o] = gA*a2A + (1.f-gA)*upd_s[aA][o];
  tmps[aB][o] = gB*a2B + (1.f-gB)*upd_s[aB][o];
  __syncthreads();
  float ouA = out_b[o], ouB = ouA;
  for (int k=0;k<128;k++){
    float w = out_w[k*128+o];
    ouA += tmps[aA][k]*w; ouB += tmps[aB][k]*w;
  }
  out[(a0+aA)*128+o] = ouA;
  out[(a0+aB)*128+o] = ouB;
}

extern "C" void kernel_launch(void* const* d_in, const int* in_sizes, int n_in,
                              void* d_out, int out_size, void* d_ws, size_t ws_size,
                              hipStream_t stream){
  const int*   atomic_numbers = (const int*)  d_in[0];
  const int*   edge_index     = (const int*)  d_in[2];
  const float* edge_vectors   = (const float*)d_in[3];
  const float* edge_lengths   = (const float*)d_in[4];
  const float* atom_embed     = (const float*)d_in[5];
  const float* rad_w1 = (const float*)d_in[6];
  const float* rad_b1 = (const float*)d_in[7];
  const float* rad_w2 = (const float*)d_in[8];
  const float* rad_b2 = (const float*)d_in[9];
  const float* tp_w   = (const float*)d_in[10];
  const float* tp_b   = (const float*)d_in[11];
  const float* msg_w1 = (const float*)d_in[12];
  const float* msg_b1 = (const float*)d_in[13];
  const float* msg_w2 = (const float*)d_in[14];
  const float* msg_b2 = (const float*)d_in[15];
  const float* attn_w_in  = (const float*)d_in[16];
  const float* attn_b_in  = (const float*)d_in[17];
  const float* attn_w_out = (const float*)d_in[18];
  const float* attn_b_out = (const float*)d_in[19];
  const float* gate_w = (const float*)d_in[20];
  const float* gate_b = (const float*)d_in[21];
  const float* out_w  = (const float*)d_in[22];
  const float* out_b  = (const float*)d_in[23];

  // workspace layout (bytes)
  char* ws = (char*)d_ws;
  int* counts    = (int*)(ws);             // [0, 16384)
  int* cursor    = (int*)(ws + 16384);     // [16384, 32768)
  int* offsets   = (int*)(ws + 32768);     // [32768, 49156)  4097 ints
  int* edge_list = (int*)(ws + 53248);     // [53248, 577536)
  float* wt_in   = (float*)(ws + 577536);  // 128x384
  float* wt_out  = (float*)(ws + 774144);  // 128x128
  float* Fp      = (float*)(ws + 839680);  // [9][4096*128] = 18.9 MB
  float* att     = (float*)(ws + 839680);  // aliases Fp (dead before attn)
  float* upd     = (float*)(ws + 19714048);// 2 MB
  float* qkv     = (float*)(ws + 21811200);// 6.3 MB  (end 28102656)

  transpose_kernel<<<256, 256, 0, stream>>>(attn_w_in, attn_w_out, wt_in, wt_out);
  hipMemsetAsync(ws, 0, 32768, stream);  // counts + cursor
  hist_kernel<<<(N_EDGES+255)/256, 256, 0, stream>>>(edge_index, counts);
  scan_kernel<<<1, 1024, 0, stream>>>(counts, offsets);
  scatter_kernel<<<(N_EDGES+255)/256, 256, 0, stream>>>(edge_index, offsets, cursor, edge_list);
  edge_F_kernel<<<N_ATOMS, 512, 0, stream>>>(edge_vectors, edge_lengths,
      rad_w1, rad_b1, rad_w2, rad_b2, offsets, edge_list, Fp);
  node_kernel<<<N_ATOMS/8, 512, 0, stream>>>(atomic_numbers, atom_embed,
      tp_w, tp_b, msg_w1, msg_b1, msg_w2, msg_b2, wt_in, attn_b_in,
      offsets, Fp, upd, qkv);
  attn_kernel<<<256, 1024, 0, stream>>>(qkv, att);
  final_kernel<<<N_ATOMS/8, 512, 0, stream>>>(att, upd, wt_out, attn_b_out,
      gate_w, gate_b, out_w, out_b, (float*)d_out);
}

// Round 7
// 366.641 us; speedup vs baseline: 2.7692x; 1.4723x over previous
//
#include <hip/hip_runtime.h>
#include <math.h>

#define N_ATOMS 4096
#define N_EDGES 131072
#define PI6 0.52359877559829887f

typedef __attribute__((ext_vector_type(8))) short bf16x8;
typedef __attribute__((ext_vector_type(4))) float f32x4;

__device__ __forceinline__ float silu_f(float x){ return x / (1.f + __expf(-x)); }
__device__ __forceinline__ float sigmoid_f(float x){ return 1.f / (1.f + __expf(-x)); }
__device__ __forceinline__ float bcastf(float v, int k){
  return __int_as_float(__builtin_amdgcn_readlane(__float_as_int(v), k));
}
__device__ __forceinline__ unsigned int f2bf(float f){
  unsigned int u = __float_as_uint(f);
  return (u + 0x7FFFu + ((u>>16)&1u)) >> 16;
}
__device__ __forceinline__ bf16x8 ld8(const unsigned short* p){
  union { unsigned int u[4]; bf16x8 v; } r;
  const unsigned int* q = (const unsigned int*)p;
  r.u[0]=q[0]; r.u[1]=q[1]; r.u[2]=q[2]; r.u[3]=q[3];
  return r.v;
}

// ---------- transpose attn_w_in (384x128) and attn_w_out (128x128) ----------
__global__ __launch_bounds__(256) void transpose_kernel(
  const float* __restrict__ win, const float* __restrict__ wout,
  float* __restrict__ wt_in, float* __restrict__ wt_out){
  int idx = blockIdx.x*256 + threadIdx.x;
  if (idx < 384*128){ int i = idx>>7, k = idx&127; wt_in[k*384+i] = win[idx]; }
  else { int j = idx - 384*128; int i = j>>7, k = j&127; wt_out[k*128+i] = wout[j]; }
}

// ---------- counting sort of edges by destination ----------
__global__ void hist_kernel(const int* __restrict__ edge_index, int* __restrict__ counts){
  int e = blockIdx.x*blockDim.x + threadIdx.x;
  if (e < N_EDGES) atomicAdd(&counts[edge_index[N_EDGES + e]], 1);
}

__global__ void scan_kernel(const int* __restrict__ counts, int* __restrict__ offsets){
  __shared__ int buf[4096];
  int t = threadIdx.x; // 1024 threads
  for (int i=t;i<4096;i+=1024) buf[i]=counts[i];
  __syncthreads();
  for (int off=1; off<4096; off<<=1){
    int v[4];
    #pragma unroll
    for (int k=0;k<4;k++){ int i=t+k*1024; v[k] = (i>=off)?buf[i-off]:0; }
    __syncthreads();
    #pragma unroll
    for (int k=0;k<4;k++){ int i=t+k*1024; buf[i]+=v[k]; }
    __syncthreads();
  }
  for (int i=t;i<4096;i+=1024) offsets[i]=buf[i]-counts[i]; // exclusive
  if (t==0) offsets[4096]=buf[4095];
}

__global__ void scatter_kernel(const int* __restrict__ edge_index, const int* __restrict__ offsets,
                               int* __restrict__ cursor, int* __restrict__ edge_list){
  int e = blockIdx.x*blockDim.x + threadIdx.x;
  if (e < N_EDGES){
    int d = edge_index[N_EDGES + e];
    int pos = atomicAdd(&cursor[d], 1);
    edge_list[offsets[d] + pos] = e;
  }
}

// ---------- per-atom edge features -> F (planar [9][N_ATOMS*128]) ----------
__global__ __launch_bounds__(512) void edge_F_kernel(
  const float* __restrict__ edge_vectors, const float* __restrict__ edge_lengths,
  const float* __restrict__ rad_w1, const float* __restrict__ rad_b1,
  const float* __restrict__ rad_w2, const float* __restrict__ rad_b2,
  const int* __restrict__ offsets, const int* __restrict__ edge_list,
  float* __restrict__ Fp)
{
  const int a = blockIdx.x, tid = threadIdx.x;
  const int g = tid >> 7;        // edge group 0..3
  const int t = tid & 127;       // channel
  const int lane = tid & 63;
  __shared__ float Fred[4][128][9];   // 18 KB

  float w2c[64], w1r[8];
  #pragma unroll
  for (int k=0;k<64;k++) w2c[k] = rad_w2[k*128 + t];
  #pragma unroll
  for (int k=0;k<8;k++)  w1r[k] = rad_w1[k*64 + lane];
  const float b1l = rad_b1[lane], b2c = rad_b2[t];
  float F9[9];
  #pragma unroll
  for (int j=0;j<9;j++) F9[j]=0.f;

  const int beg = offsets[a], end = offsets[a+1];
  for (int ei=beg+g; ei<end; ei+=4){
    int e = __builtin_amdgcn_readfirstlane(edge_list[ei]);
    float vx = edge_vectors[e*3], vy = edge_vectors[e*3+1], vz = edge_vectors[e*3+2];
    float d  = edge_lengths[e];
    float rn = sqrtf(vx*vx+vy*vy+vz*vz) + 1e-8f;
    float x = vx/rn, y = vy/rn, z = vz/rn;
    float sh[9] = {1.f, y, z, x, 3.f*z*z-1.f, x*z, y*z, x*y, x*x-y*y};
    float rb = 0.f;
    if (lane < 8){
      float cut = 0.5f*(__cosf(d*PI6)+1.f)*(d<6.f?1.f:0.f);
      rb = __sinf(d*((float)(lane+1)*PI6))/d*cut;
    }
    float pa = b1l, pb = 0.f;
    #pragma unroll
    for (int k=0;k<8;k+=2){
      pa += bcastf(rb,k)*w1r[k];
      pb += bcastf(rb,k+1)*w1r[k+1];
    }
    float r1 = silu_f(pa+pb);
    float r2a=b2c, r2b=0.f, r2c=0.f, r2d=0.f;
    #pragma unroll
    for (int k=0;k<64;k+=4){
      r2a += bcastf(r1,k  )*w2c[k  ];
      r2b += bcastf(r1,k+1)*w2c[k+1];
      r2c += bcastf(r1,k+2)*w2c[k+2];
      r2d += bcastf(r1,k+3)*w2c[k+3];
    }
    float r2 = silu_f((r2a+r2b)+(r2c+r2d));
    #pragma unroll
    for (int j=0;j<9;j++) F9[j] += r2*sh[j];
  }

  #pragma unroll
  for (int j=0;j<9;j++) Fred[g][t][j] = F9[j];
  __syncthreads();
  if (g==0){
    #pragma unroll
    for (int j=0;j<9;j++)
      Fp[j*(N_ATOMS*128) + a*128 + t] = F9[j] + Fred[1][t][j] + Fred[2][t][j] + Fred[3][t][j];
  }
}

// ---------- node update: agg -> msg MLP -> qkv ; 8 atoms, 512 threads ----------
__global__ __launch_bounds__(512) void node_kernel(
  const int* __restrict__ atomic_numbers, const float* __restrict__ atom_embed,
  const float* __restrict__ tp_w, const float* __restrict__ tp_b,
  const float* __restrict__ msg_w1, const float* __restrict__ msg_b1,
  const float* __restrict__ msg_w2, const float* __restrict__ msg_b2,
  const float* __restrict__ wt_in, const float* __restrict__ attn_b_in,
  const int* __restrict__ offsets, const float* __restrict__ Fp,
  float* __restrict__ upd_out, float* __restrict__ qkv_out)
{
  const int a0 = blockIdx.x*8, tid = threadIdx.x;
  const int g = tid >> 7, o = tid & 127;
  __shared__ float red[4][8][128];   // 16 KB
  __shared__ float combs[8][192];
  __shared__ float hids[8][128];
  __shared__ float upds[8][128];

  float acc[8];
  #pragma unroll
  for (int a8=0;a8<8;a8++) acc[a8] = 0.f;

  const float4* Fp4 = (const float4*)Fp;
  for (int c4=g*8; c4<g*8+8; c4++){
    #pragma unroll
    for (int j=0;j<9;j++){
      float4 f[8];
      #pragma unroll
      for (int a8=0;a8<8;a8++) f[a8] = Fp4[j*(N_ATOMS*32) + (a0+a8)*32 + c4];
      #pragma unroll
      for (int cc=0;cc<4;cc++){
        int c = c4*4+cc;
        int row = (j==0)? c : (j<4 ? 128 + c*3 + (j-1) : 512 + c*5 + (j-4));
        float w = tp_w[row*128+o];
        #pragma unroll
        for (int a8=0;a8<8;a8++){
          float fv = (cc==0)?f[a8].x:(cc==1)?f[a8].y:(cc==2)?f[a8].z:f[a8].w;
          acc[a8] += fv*w;
        }
      }
    }
  }
  #pragma unroll
  for (int a8=0;a8<8;a8++) red[g][a8][o] = acc[a8];
  { int a8 = tid>>6, k = tid&63;
    combs[a8][k] = atom_embed[atomic_numbers[a0+a8]*64 + k]; }
  __syncthreads();
  if (g==0){
    const float tb = tp_b[o];
    #pragma unroll
    for (int a8=0;a8<8;a8++){
      float deg = (float)(offsets[a0+a8+1]-offsets[a0+a8]);
      combs[a8][64+o] = red[0][a8][o]+red[1][a8][o]+red[2][a8][o]+red[3][a8][o] + tb*deg;
    }
  }
  __syncthreads();

  const int aA = 2*g, aB = 2*g+1;
  {
    float hA = msg_b1[o], hB = hA;
    for (int k=0;k<192;k++){
      float w = msg_w1[k*128+o];
      hA += combs[aA][k]*w; hB += combs[aB][k]*w;
    }
    hids[aA][o] = silu_f(hA); hids[aB][o] = silu_f(hB);
  }
  __syncthreads();
  {
    float uA = msg_b2[o], uB = uA;
    for (int k=0;k<128;k++){
      float w = msg_w2[k*128+o];
      uA += hids[aA][k]*w; uB += hids[aB][k]*w;
    }
    upds[aA][o]=uA; upds[aB][o]=uB;
    upd_out[(a0+aA)*128+o]=uA; upd_out[(a0+aB)*128+o]=uB;
  }
  __syncthreads();
  for (int p=0;p<3;p++){
    float qA = attn_b_in[p*128+o], qB = qA;
    for (int k=0;k<128;k++){
      float w = wt_in[k*384 + p*128 + o];
      qA += upds[aA][k]*w; qB += upds[aB][k]*w;
    }
    qkv_out[(a0+aA)*384 + p*128 + o] = qA;
    qkv_out[(a0+aB)*384 + p*128 + o] = qB;
  }
}

// ---------- MFMA flash attention: 4 heads, N=4096, D=32, bf16 matmuls ----------
// block: 32 queries x 1 head, 256 thr = 8 waves = (2 q-groups) x (2 key-halves)
__global__ __launch_bounds__(256) void attn_kernel(const float* __restrict__ qkv, float* __restrict__ att){
  const int b = blockIdx.x;
  const int h = b >> 7, qt = b & 127;      // 4 heads, 128 q-tiles of 32
  const int tid = threadIdx.x;
  const int w = tid >> 6, lane = tid & 63;
  const int wq = w & 1, wk = w >> 1;       // query group, key half
  const int l15 = lane & 15, lg = lane >> 4;
  const int n0 = qt*32;

  __shared__ unsigned short Qs[32][36];
  __shared__ unsigned short Ks[2][2][64][36];
  __shared__ unsigned short Vt[2][2][32][66];
  __shared__ unsigned short Ps[8][16][68];
  __shared__ float MB[2][64][16];

  const float scale = 0.17677669529663687f; // 1/sqrt(32)

  // ---- stage Q (scaled) ----
  {
    int qr = tid>>3, d4 = (tid&7)*4;
    const float4 qf = *(const float4*)(qkv + (size_t)(n0+qr)*384 + h*32 + d4);
    unsigned int* dst = (unsigned int*)&Qs[qr][d4];
    dst[0] = f2bf(qf.x*scale) | (f2bf(qf.y*scale)<<16);
    dst[1] = f2bf(qf.z*scale) | (f2bf(qf.w*scale)<<16);
  }

  // staging thread mapping: half hf = tid>>7 stages tile (hf*32 + t)
  const int hf = tid >> 7, u = tid & 127;
  const int skey = u >> 1, sd16 = (u & 1)*16;
  float4 kA,kB,kC,kD, vA,vB,vC,vD;

  #define LOADG(T) { \
    const float* kp = qkv + (size_t)(((hf*32+(T))*64 + skey))*384 + 128 + h*32 + sd16; \
    kA = *(const float4*)kp;        kB = *(const float4*)(kp+4); \
    kC = *(const float4*)(kp+8);    kD = *(const float4*)(kp+12); \
    const float* vp = kp + 128; \
    vA = *(const float4*)vp;        vB = *(const float4*)(vp+4); \
    vC = *(const float4*)(vp+8);    vD = *(const float4*)(vp+12); }

  #define WRITEL(BUF) { \
    unsigned int* kdst = (unsigned int*)&Ks[BUF][hf][skey][sd16]; \
    kdst[0]=f2bf(kA.x)|(f2bf(kA.y)<<16); kdst[1]=f2bf(kA.z)|(f2bf(kA.w)<<16); \
    kdst[2]=f2bf(kB.x)|(f2bf(kB.y)<<16); kdst[3]=f2bf(kB.z)|(f2bf(kB.w)<<16); \
    kdst[4]=f2bf(kC.x)|(f2bf(kC.y)<<16); kdst[5]=f2bf(kC.z)|(f2bf(kC.w)<<16); \
    kdst[6]=f2bf(kD.x)|(f2bf(kD.y)<<16); kdst[7]=f2bf(kD.z)|(f2bf(kD.w)<<16); \
    Vt[BUF][hf][sd16+ 0][skey]=(unsigned short)f2bf(vA.x); \
    Vt[BUF][hf][sd16+ 1][skey]=(unsigned short)f2bf(vA.y); \
    Vt[BUF][hf][sd16+ 2][skey]=(unsigned short)f2bf(vA.z); \
    Vt[BUF][hf][sd16+ 3][skey]=(unsigned short)f2bf(vA.w); \
    Vt[BUF][hf][sd16+ 4][skey]=(unsigned short)f2bf(vB.x); \
    Vt[BUF][hf][sd16+ 5][skey]=(unsigned short)f2bf(vB.y); \
    Vt[BUF][hf][sd16+ 6][skey]=(unsigned short)f2bf(vB.z); \
    Vt[BUF][hf][sd16+ 7][skey]=(unsigned short)f2bf(vB.w); \
    Vt[BUF][hf][sd16+ 8][skey]=(unsigned short)f2bf(vC.x); \
    Vt[BUF][hf][sd16+ 9][skey]=(unsigned short)f2bf(vC.y); \
    Vt[BUF][hf][sd16+10][skey]=(unsigned short)f2bf(vC.z); \
    Vt[BUF][hf][sd16+11][skey]=(unsigned short)f2bf(vC.w); \
    Vt[BUF][hf][sd16+12][skey]=(unsigned short)f2bf(vD.x); \
    Vt[BUF][hf][sd16+13][skey]=(unsigned short)f2bf(vD.y); \
    Vt[BUF][hf][sd16+14][skey]=(unsigned short)f2bf(vD.z); \
    Vt[BUF][hf][sd16+15][skey]=(unsigned short)f2bf(vD.w); }

  LOADG(0);
  WRITEL(0);
  __syncthreads();

  // A-fragment for Q (after barrier so Qs is complete)
  bf16x8 aQ = ld8(&Qs[wq*16 + l15][lg*8]);

  float m[4] = {-3e38f,-3e38f,-3e38f,-3e38f};
  float su[4] = {0.f,0.f,0.f,0.f};
  f32x4 oacc[2] = {{0.f,0.f,0.f,0.f},{0.f,0.f,0.f,0.f}};

  for (int t=0; t<32; t++){
    const int cur = t&1;
    if (t<31) LOADG(t+1);

    // QK^T: 4 MFMA, S tile 16q x 64k
    f32x4 s[4];
    #pragma unroll
    for (int n=0;n<4;n++){
      bf16x8 bK = ld8(&Ks[cur][wk][n*16+l15][lg*8]);
      f32x4 z = {0.f,0.f,0.f,0.f};
      s[n] = __builtin_amdgcn_mfma_f32_16x16x32_bf16(aQ, bK, z, 0,0,0);
    }

    // online softmax
    float csc[4], psum[4];
    #pragma unroll
    for (int r=0;r<4;r++){
      float mloc = fmaxf(fmaxf(s[0][r], s[1][r]), fmaxf(s[2][r], s[3][r]));
      #pragma unroll
      for (int off=1; off<16; off<<=1) mloc = fmaxf(mloc, __shfl_xor(mloc, off, 64));
      float mn = fmaxf(m[r], mloc);
      csc[r] = __expf(m[r] - mn);
      m[r] = mn;
      psum[r] = 0.f;
    }
    #pragma unroll
    for (int n=0;n<4;n++){
      #pragma unroll
      for (int r=0;r<4;r++){
        float p = __expf(s[n][r] - m[r]);
        psum[r] += p;
        Ps[w][lg*4+r][n*16+l15] = (unsigned short)f2bf(p);
      }
    }
    #pragma unroll
    for (int r=0;r<4;r++){
      #pragma unroll
      for (int off=1; off<16; off<<=1) psum[r] += __shfl_xor(psum[r], off, 64);
      su[r] = su[r]*csc[r] + psum[r];
    }
    #pragma unroll
    for (int nd=0;nd<2;nd++){
      #pragma unroll
      for (int r=0;r<4;r++) oacc[nd][r] *= csc[r];
    }

    // PV: O(16q x 32d) += P(16x64) * V(64x32)
    #pragma unroll
    for (int c=0;c<2;c++){
      bf16x8 aP = ld8(&Ps[w][l15][c*32 + lg*8]);
      #pragma unroll
      for (int nd=0;nd<2;nd++){
        bf16x8 bV = ld8(&Vt[cur][wk][nd*16+l15][c*32 + lg*8]);
        oacc[nd] = __builtin_amdgcn_mfma_f32_16x16x32_bf16(aP, bV, oacc[nd], 0,0,0);
      }
    }

    __syncthreads();
    if (t<31) WRITEL((t+1)&1);
    __syncthreads();
  }

  // merge key-halves: wk=1 publishes, wk=0 merges and writes out
  if (wk==1){
    #pragma unroll
    for (int r=0;r<4;r++){ MB[wq][lane][r] = m[r]; MB[wq][lane][4+r] = su[r]; }
    #pragma unroll
    for (int nd=0;nd<2;nd++)
      #pragma unroll
      for (int r=0;r<4;r++) MB[wq][lane][8+nd*4+r] = oacc[nd][r];
  }
  __syncthreads();
  if (wk==0){
    #pragma unroll
    for (int r=0;r<4;r++){
      float m1 = MB[wq][lane][r], s1 = MB[wq][lane][4+r];
      float mf = fmaxf(m[r], m1);
      float c0 = __expf(m[r]-mf), c1 = __expf(m1-mf);
      float stot = su[r]*c0 + s1*c1;
      float inv = 1.f/stot;
      #pragma unroll
      for (int nd=0;nd<2;nd++){
        float o = oacc[nd][r]*c0 + MB[wq][lane][8+nd*4+r]*c1;
        att[(size_t)(n0 + wq*16 + lg*4 + r)*128 + h*32 + nd*16 + l15] = o*inv;
      }
    }
  }
  #undef LOADG
  #undef WRITEL
}

// ---------- epilogue: 8 atoms, 512 threads, LDS-staged operands ----------
__global__ __launch_bounds__(512) void final_kernel(
  const float* __restrict__ att, const float* __restrict__ upd,
  const float* __restrict__ wt_out, const float* __restrict__ attn_b_out,
  const float* __restrict__ gate_w, const float* __restrict__ gate_b,
  const float* __restrict__ out_w, const float* __restrict__ out_b,
  float* __restrict__ out)
{
  const int a0 = blockIdx.x*8, tid = threadIdx.x;
  const int g = tid >> 7, o = tid & 127;
  __shared__ float att_s[8][128], upd_s[8][128], tmps[8][128];
  for (int i=tid; i<1024; i+=512){
    int a8 = i>>7, k = i&127;
    att_s[a8][k] = att[(a0+a8)*128+k];
    upd_s[a8][k] = upd[(a0+a8)*128+k];
  }
  __syncthreads();
  const int aA = 2*g, aB = 2*g+1;
  float a2A = attn_b_out[o], a2B = a2A;
  float gA = gate_b[o], gB = gA;
  for (int k=0;k<128;k++){
    float wa = wt_out[k*128+o];
    float wg = gate_w[k*128+o];
    a2A += att_s[aA][k]*wa; a2B += att_s[aB][k]*wa;
    gA  += upd_s[aA][k]*wg; gB  += upd_s[aB][k]*wg;
  }
  gA = sigmoid_f(gA); gB = sigmoid_f(gB);
  tmps[aA][o] = gA*a2A + (1.f-gA)*upd_s[aA][o];
  tmps[aB][o] = gB*a2B + (1.f-gB)*upd_s[aB][o];
  __syncthreads();
  float ouA = out_b[o], ouB = ouA;
  for (int k=0;k<128;k++){
    float w = out_w[k*128+o];
    ouA += tmps[aA][k]*w; ouB += tmps[aB][k]*w;
  }
  out[(a0+aA)*128+o] = ouA;
  out[(a0+aB)*128+o] = ouB;
}

extern "C" void kernel_launch(void* const* d_in, const int* in_sizes, int n_in,
                              void* d_out, int out_size, void* d_ws, size_t ws_size,
                              hipStream_t stream){
  const int*   atomic_numbers = (const int*)  d_in[0];
  const int*   edge_index     = (const int*)  d_in[2];
  const float* edge_vectors   = (const float*)d_in[3];
  const float* edge_lengths   = (const float*)d_in[4];
  const float* atom_embed     = (const float*)d_in[5];
  const float* rad_w1 = (const float*)d_in[6];
  const float* rad_b1 = (const float*)d_in[7];
  const float* rad_w2 = (const float*)d_in[8];
  const float* rad_b2 = (const float*)d_in[9];
  const float* tp_w   = (const float*)d_in[10];
  const float* tp_b   = (const float*)d_in[11];
  const float* msg_w1 = (const float*)d_in[12];
  const float* msg_b1 = (const float*)d_in[13];
  const float* msg_w2 = (const float*)d_in[14];
  const float* msg_b2 = (const float*)d_in[15];
  const float* attn_w_in  = (const float*)d_in[16];
  const float* attn_b_in  = (const float*)d_in[17];
  const float* attn_w_out = (const float*)d_in[18];
  const float* attn_b_out = (const float*)d_in[19];
  const float* gate_w = (const float*)d_in[20];
  const float* gate_b = (const float*)d_in[21];
  const float* out_w  = (const float*)d_in[22];
  const float* out_b  = (const float*)d_in[23];

  // workspace layout (bytes)
  char* ws = (char*)d_ws;
  int* counts    = (int*)(ws);             // [0, 16384)
  int* cursor    = (int*)(ws + 16384);     // [16384, 32768)
  int* offsets   = (int*)(ws + 32768);     // [32768, 49156)  4097 ints
  int* edge_list = (int*)(ws + 53248);     // [53248, 577536)
  float* wt_in   = (float*)(ws + 577536);  // 128x384
  float* wt_out  = (float*)(ws + 774144);  // 128x128
  float* Fp      = (float*)(ws + 839680);  // [9][4096*128] = 18.9 MB
  float* att     = (float*)(ws + 839680);  // aliases Fp (dead before attn)
  float* upd     = (float*)(ws + 19714048);// 2 MB
  float* qkv     = (float*)(ws + 21811200);// 6.3 MB  (end 28102656)

  transpose_kernel<<<256, 256, 0, stream>>>(attn_w_in, attn_w_out, wt_in, wt_out);
  hipMemsetAsync(ws, 0, 32768, stream);  // counts + cursor
  hist_kernel<<<(N_EDGES+255)/256, 256, 0, stream>>>(edge_index, counts);
  scan_kernel<<<1, 1024, 0, stream>>>(counts, offsets);
  scatter_kernel<<<(N_EDGES+255)/256, 256, 0, stream>>>(edge_index, offsets, cursor, edge_list);
  edge_F_kernel<<<N_ATOMS, 512, 0, stream>>>(edge_vectors, edge_lengths,
      rad_w1, rad_b1, rad_w2, rad_b2, offsets, edge_list, Fp);
  node_kernel<<<N_ATOMS/8, 512, 0, stream>>>(atomic_numbers, atom_embed,
      tp_w, tp_b, msg_w1, msg_b1, msg_w2, msg_b2, wt_in, attn_b_in,
      offsets, Fp, upd, qkv);
  attn_kernel<<<512, 256, 0, stream>>>(qkv, att);
  final_kernel<<<N_ATOMS/8, 512, 0, stream>>>(att, upd, wt_out, attn_b_out,
      gate_w, gate_b, out_w, out_b, (float*)d_out);
}